// Round 7
// baseline (300.048 us; speedup 1.0000x reference)
//
#include <hip/hip_runtime.h>
#include <hip/hip_bf16.h>

// B=8, T=4096, C=384, H=64 causal single-head attention. fp32 in/out.
//
// Round-19: attn K-stream register double-buffer. Round-18: qkv dropped out
// of the top-5 (Wt pipeline worked); attn is the sole #1 at ~50us with
// VALUBusy 35% / MfmaUtil 13% / ~50% stall. Capacity check: 4 waves/SIMD x
// 16.25 tiles x ~330 VALU x 2cy ~= 42k cy == measured VALU-busy -> work is
// real, pipe is underfed. The feed gap: 8 ka fragment loads issue at
// iteration start and are consumed immediately by QK -> 200-400cy L2
// latency exposed every tile. Fix: prefetch tile t+4's ka into a second
// register buffer (kaA/kaB ping-pong, static names, manual 2x unroll)
// during tile t's softmax/PV. vb loads move to just-after-QK so peak live
// regs ~116 < 128 (16-wave block requires <=128 for 4 waves/SIMD).
// qkv (r18 Wt pipeline), wtrans, all layouts unchanged.
//
//  k_frag layout: [blk64][st][c8=h/8][i=m][j=h%8], row m of st holds
//                 K row s = 32*(st>>1) + 8*(m>>2) + 4*(st&1) + (m&3)
//  vt_frag layout: [st=row/64][dt=d/16][sc=s%64/8][i=d%16][j=s%8]

typedef __bf16 bf16x8 __attribute__((ext_vector_type(8)));
typedef float  f32x4  __attribute__((ext_vector_type(4)));

#define BB   8
#define TT   4096
#define CC   384
#define HH   64
#define NROW (BB*TT)       // 32768
// C^-0.5 * log2(e): fold softmax scale + exp2 conversion into q at projection
#define QSCALE (0.05103103630798288f * 1.4426950408889634f)

#if __has_builtin(__builtin_amdgcn_exp2f)
#define EXP2(x) __builtin_amdgcn_exp2f(x)
#else
#define EXP2(x) exp2f(x)
#endif

__device__ __forceinline__ unsigned short f2bf(float f) {
    __bf16 h = (__bf16)f;
    return __builtin_bit_cast(unsigned short, h);
}

// ---------------------------------------------------------------- kernel 1
// Wt[mat][h][c] = bf16(W[mat][c][h]), via LDS tile (coalesced both sides).
__global__ __launch_bounds__(256) void wtrans_kernel(
        const float* __restrict__ Wk,
        const float* __restrict__ Wq,
        const float* __restrict__ Wv,
        unsigned short* __restrict__ Wt) {
    __shared__ __align__(16) unsigned short tile[64][72];
    const float* Wm = (blockIdx.y == 0) ? Wk : ((blockIdx.y == 1) ? Wq : Wv);
    unsigned short* Wtm = Wt + blockIdx.y * (HH * CC);
    const int c0 = blockIdx.x * 64;
#pragma unroll
    for (int i = 0; i < 16; ++i) {
        int id = threadIdx.x + i * 256;         // 0..4095
        int c = id >> 6, h = id & 63;
        tile[c][h] = f2bf(Wm[(c0 + c) * HH + h]);   // coalesced read
    }
    __syncthreads();
#pragma unroll
    for (int i = 0; i < 16; ++i) {
        int id = threadIdx.x + i * 256;
        int h = id >> 6, c = id & 63;
        Wtm[h * CC + c0 + c] = tile[c][h];      // coalesced write
    }
}

// ---------------------------------------------------------------- kernel 2
// QKV projection: [32768,384]x[384,64] x3 with 16x16x32 bf16 MFMA.
// 1024 blocks x 256 thr; block = 32 rows. 4 waves = 2 row-tiles x 2 h-halves.
// ALL of x staged fp32 into LDS by 12 global_load_lds per wave (one vmcnt +
// one barrier). Wt consumed through a depth-12 register pipeline: bf[2][12],
// chunk kk+1 prefetched while chunk kk computes. k/q/vt epilogue layouts
// identical to round-15.
__global__ __launch_bounds__(256, 1) void qkv_kernel(
        const float* __restrict__ x,
        const unsigned short* __restrict__ Wt,     // [3][64][384] bf16
        unsigned short* __restrict__ q_ws,         // [32768][64] row-major, pre-scaled
        unsigned short* __restrict__ k_ws,         // fragment layout (permuted)
        unsigned short* __restrict__ vt_ws) {      // fragment layout
    // xs[chunk][local row][64 floats]; 16B slot p of (chunk,row) holds global
    // sub-chunk p ^ (row&7). 48 KB, chunk-major so each 1KB DMA instruction
    // (4 rows x 256B) is contiguous.
    __shared__ __align__(16) float xs[6][32][64];               // 49152 B
    __shared__ __align__(16) unsigned short vtile[64][40];      //  5120 B

    const int lane = threadIdx.x & 63;
    const int wv   = threadIdx.x >> 6;     // 0..3
    const int rt   = wv & 1;               // row-tile (16 rows)
    const int hh   = wv >> 1;              // h-half (2 nt)
    const int l15  = lane & 15;
    const int quad = lane >> 4;
    const int rb   = blockIdx.x * 32;
    const int ntb  = hh * 2;               // first of this wave's two nt

    // ---- stage ALL 6 chunks: 12 independent DMA instructions per wave ----
#pragma unroll
    for (int kk = 0; kk < 6; ++kk) {
#pragma unroll
        for (int j = 0; j < 2; ++j) {
            const int r0 = wv * 8 + j * 4;                 // instr's first row
            const int r  = r0 + quad;                      // this lane's row
            const int ch = l15 ^ (r & 7);                  // swizzled src chunk
            const float* src = x + (long)(rb + r) * CC + kk * 64 + ch * 4;
            float* dst = &xs[kk][r0][0];                   // linear: +lane*16B
            __builtin_amdgcn_global_load_lds(
                (const __attribute__((address_space(1))) unsigned int*)src,
                (__attribute__((address_space(3))) unsigned int*)dst,
                16, 0, 0);
        }
    }

    // ---- Wt register pipeline: 12 fragments per 64-col chunk ----
    bf16x8 bf[2][12];
    auto loadW = [&](int kk, bf16x8* dst) {
#pragma unroll
        for (int m = 0; m < 3; ++m)
#pragma unroll
            for (int n = 0; n < 2; ++n)
#pragma unroll
                for (int h01 = 0; h01 < 2; ++h01)
                    dst[m * 4 + n * 2 + h01] = *reinterpret_cast<const bf16x8*>(
                        Wt + m * (HH * CC) + ((ntb + n) * 16 + l15) * CC
                          + kk * 64 + h01 * 32 + quad * 8);
    };
    loadW(0, bf[0]);

    f32x4 acc[3][2];
    const f32x4 zero = {0.f, 0.f, 0.f, 0.f};
#pragma unroll
    for (int m = 0; m < 3; ++m)
#pragma unroll
        for (int n = 0; n < 2; ++n) acc[m][n] = zero;

    const int rloc = rt * 16 + l15;        // A-frag row (local)
    const int rx7  = rloc & 7;

    __asm volatile("s_waitcnt vmcnt(0)" ::: "memory");  // x DMA + bf[0]
    __syncthreads();

#pragma unroll
    for (int kk = 0; kk < 6; ++kk) {
        if (kk < 5) loadW(kk + 1, bf[(kk + 1) & 1]);   // 12 loads in flight
#pragma unroll
        for (int h01 = 0; h01 < 2; ++h01) {
            const int chb = 8 * h01 + 2 * quad;
            const f32x4 xa = *reinterpret_cast<const f32x4*>(
                &xs[kk][rloc][((chb) ^ rx7) * 4]);
            const f32x4 xb = *reinterpret_cast<const f32x4*>(
                &xs[kk][rloc][((chb + 1) ^ rx7) * 4]);
            bf16x8 a;
#pragma unroll
            for (int e = 0; e < 4; ++e) {
                a[e]     = (__bf16)xa[e];
                a[4 + e] = (__bf16)xb[e];
            }
#pragma unroll
            for (int m = 0; m < 3; ++m)
#pragma unroll
                for (int n = 0; n < 2; ++n)
                    acc[m][n] = __builtin_amdgcn_mfma_f32_16x16x32_bf16(
                        a, bf[kk & 1][m * 4 + n * 2 + h01], acc[m][n], 0, 0, 0);
        }
    }

    // Epilogue. C-layout: acc[m][n][r] = out[local row quad*4+r][h=(ntb+n)*16+l15]
#pragma unroll
    for (int n = 0; n < 2; ++n) {
        const int nt = ntb + n;
        const int h  = nt * 16 + l15;
        const int c8 = h >> 3;
        const int jj = h & 7;
#pragma unroll
        for (int r = 0; r < 4; ++r) {
            const int gr = rb + rt * 16 + quad * 4 + r;
            // k: permuted fragment position for local row s = gr & 63
            const int s   = gr & 63;
            const int stp = ((s >> 4) & 2) + ((s >> 2) & 1); // 2*(s>>5)+bit2
            const int ip  = ((s >> 1) & 12) + (s & 3);       // 4*((s>>3)&3)+(s&3)
            k_ws[(long)(gr >> 6) * 4096 + stp * 1024 + c8 * 128 + ip * 8 + jj]
                = f2bf(acc[0][n][r]);
            q_ws[gr * HH + h] = f2bf(acc[1][n][r] * QSCALE);
            vtile[h][rt * 16 + quad * 4 + r] = f2bf(acc[2][n][r]);
        }
    }
    __syncthreads();
    // vt fragment store: block covers sc-half (rb&32)>>3 of its 64-blk.
    {
        const int id  = threadIdx.x;               // 0..255
        const int dt  = id >> 6, scl = (id >> 4) & 3, ii = id & 15;
        const int sc  = scl + ((rb >> 3) & 4);
        unsigned short* dst = vt_ws + (long)(rb >> 6) * 4096
                              + (dt * 8 + sc) * 128 + ii * 8;
        *reinterpret_cast<uint4*>(dst) =
            *reinterpret_cast<const uint4*>(&vtile[dt * 16 + ii][scl * 8]);
    }
}

// ---------------------------------------------------------------- kernel 3
// Flash attention. 256 blocks x 1024 thr; block (p,b) does q-tile A=63-p
// then B=p (65 k-tiles constant). 16 waves = 4 groups x 4 waves; group g
// takes tiles t = 4j+g. Barrier-free k-loop, P entirely in registers;
// K stream register-double-buffered (ka for t+4 prefetched during t's
// softmax/PV); vb loaded after QK (softmax covers its latency).
__global__ __launch_bounds__(1024, 4) void attn_kernel(
        const unsigned short* __restrict__ q_ws,
        const unsigned short* __restrict__ k_ws,   // permuted fragment layout
        const unsigned short* __restrict__ vt_ws,  // fragment layout
        float* __restrict__ out) {
    __shared__ __align__(16) float xchg[64 * 65];                // 16640 B
    __shared__ float mx1[64], lx1[64];

    const int lane = threadIdx.x & 63;
    const int wv16 = threadIdx.x >> 6;     // 0..15
    const int grp  = wv16 >> 2;            // wave-group 0..3
    const int wg   = wv16 & 3;             // wave within group
    const int l15  = lane & 15;
    const int quad = lane >> 4;

    const int bid = blockIdx.x;
    const int b   = bid & 7;               // batch <-> XCD affinity
    const int p   = bid >> 3;              // 0..31

    const f32x4 zero = {0.f, 0.f, 0.f, 0.f};

    // -------- load the 8 K fragments of k-tile t into ka[0..7] --------
    auto load_k = [&](int t, bf16x8* ka) {
        const unsigned short* ktile = k_ws + ((long)((b * TT + t * 64) >> 4)) * 1024;
#pragma unroll
        for (int st = 0; st < 4; ++st) {
            ka[st]     = *reinterpret_cast<const bf16x8*>(
                ktile + ((st * 8 + quad) * 16 + l15) * 8);
            ka[4 + st] = *reinterpret_cast<const bf16x8*>(
                ktile + ((st * 8 + 4 + quad) * 16 + l15) * 8);
        }
    };

    // -------- one k-tile of phase with q-tile `qt` (ka preloaded) --------
    auto do_tile = [&](int t, int qt, int qrow,
                       const bf16x8& qf0, const bf16x8& qf1, const bf16x8* ka,
                       f32x4* o, float& mprev, float& lsum) {
        const int s0 = t * 64;
        const unsigned short* vtile = vt_ws + ((long)((b * TT + s0) >> 6)) * 4096;

        f32x4 sc[4];
#pragma unroll
        for (int st = 0; st < 4; ++st) {
            f32x4 z = zero;
            z = __builtin_amdgcn_mfma_f32_16x16x32_bf16(ka[st], qf0, z, 0, 0, 0);
            z = __builtin_amdgcn_mfma_f32_16x16x32_bf16(ka[4 + st], qf1, z, 0, 0, 0);
            sc[st] = z;
        }

        // vb issued after QK: softmax (~400cy) covers L2 latency before PV.
        bf16x8 vb0[4], vb1[4];
#pragma unroll
        for (int dt = 0; dt < 4; ++dt) {
            vb0[dt] = *reinterpret_cast<const bf16x8*>(
                vtile + dt * 1024 + quad * 128 + l15 * 8);
            vb1[dt] = *reinterpret_cast<const bf16x8*>(
                vtile + dt * 1024 + (4 + quad) * 128 + l15 * 8);
        }

        if (t == qt) {                    // causal mask, diagonal tile only
            // permuted row map: s_local = 32*(st>>1) + 8*quad + 4*(st&1) + r
#pragma unroll
            for (int st = 0; st < 4; ++st)
#pragma unroll
                for (int r = 0; r < 4; ++r) {
                    int sg = s0 + ((st >> 1) << 5) + (quad << 3)
                               + ((st & 1) << 2) + r;
                    if (sg > qrow) sc[st][r] = -1e30f;
                }
        }

        float mloc = -1e30f;
#pragma unroll
        for (int st = 0; st < 4; ++st)
#pragma unroll
            for (int r = 0; r < 4; ++r) mloc = fmaxf(mloc, sc[st][r]);
        mloc = fmaxf(mloc, __shfl_xor(mloc, 16));
        mloc = fmaxf(mloc, __shfl_xor(mloc, 32));
        const float mnew = fmaxf(mprev, mloc);
        const unsigned long long anych = __ballot(mnew > mprev);
        float alpha = 1.0f;
        if (anych) alpha = EXP2(mprev - mnew);

        float psum = 0.f;
#pragma unroll
        for (int st = 0; st < 4; ++st)
#pragma unroll
            for (int r = 0; r < 4; ++r) {
                float pv = EXP2(sc[st][r] - mnew);
                psum += pv;
                sc[st][r] = pv;
            }
        psum += __shfl_xor(psum, 16);
        psum += __shfl_xor(psum, 32);
        lsum = lsum * alpha + psum;
        mprev = mnew;

        if (anych) {
            float ar[4];
#pragma unroll
            for (int r = 0; r < 4; ++r) ar[r] = __shfl(alpha, quad * 4 + r);
#pragma unroll
            for (int dt = 0; dt < 4; ++dt)
#pragma unroll
                for (int r = 0; r < 4; ++r) o[dt][r] *= ar[r];
        }

        // P in-register: sc[st][r] already in PV A-fragment order.
        bf16x8 pf0, pf1;
#pragma unroll
        for (int r = 0; r < 4; ++r) {
            pf0[r]     = (__bf16)sc[0][r];
            pf0[4 + r] = (__bf16)sc[1][r];
            pf1[r]     = (__bf16)sc[2][r];
            pf1[4 + r] = (__bf16)sc[3][r];
        }
#pragma unroll
        for (int dt = 0; dt < 4; ++dt) {
            o[dt] = __builtin_amdgcn_mfma_f32_16x16x32_bf16(pf0, vb0[dt], o[dt], 0, 0, 0);
            o[dt] = __builtin_amdgcn_mfma_f32_16x16x32_bf16(pf1, vb1[dt], o[dt], 0, 0, 0);
        }
    };

    // -------- run one phase: dbuf'd k-loop (kaA/kaB ping-pong) --------
    auto run_phase = [&](int qt, int qrow,
                         const bf16x8& qf0, const bf16x8& qf1,
                         f32x4* o, float& mprev, float& lsum) {
        if (grp > qt) return;
        bf16x8 kaA[8], kaB[8];
        load_k(grp, kaA);
        int t = grp;
        for (;;) {
            if (t + 4 <= qt) load_k(t + 4, kaB);   // prefetch next
            do_tile(t, qt, qrow, qf0, qf1, kaA, o, mprev, lsum);
            t += 4;
            if (t > qt) break;
            if (t + 4 <= qt) load_k(t + 4, kaA);   // prefetch next
            do_tile(t, qt, qrow, qf0, qf1, kaB, o, mprev, lsum);
            t += 4;
            if (t > qt) break;
        }
    };

    // -------- merge groups 1..3 into group 0, then store q-tile `qt` --------
    auto merge_store = [&](int qt, f32x4* o, float& mprev, float& lsum) {
        for (int rr = 1; rr < 4; ++rr) {
            __syncthreads();
            if (grp == rr) {
                if (quad == 0) { mx1[wg * 16 + l15] = mprev; lx1[wg * 16 + l15] = lsum; }
#pragma unroll
                for (int dt = 0; dt < 4; ++dt)
#pragma unroll
                    for (int r = 0; r < 4; ++r)
                        xchg[(wg * 16 + quad * 4 + r) * 65 + dt * 16 + l15] = o[dt][r];
            }
            __syncthreads();
            if (grp == 0) {
#pragma unroll
                for (int r = 0; r < 4; ++r) {
                    const int row = wg * 16 + quad * 4 + r;
                    const float m0r = __shfl(mprev, quad * 4 + r);
                    const float m1r = mx1[row];
                    const float ms  = fmaxf(m0r, m1r);
                    const float w0  = EXP2(m0r - ms);
                    const float w1  = EXP2(m1r - ms);
#pragma unroll
                    for (int dt = 0; dt < 4; ++dt)
                        o[dt][r] = o[dt][r] * w0 + xchg[row * 65 + dt * 16 + l15] * w1;
                }
                const float m1l = mx1[wg * 16 + l15];
                const float msl = fmaxf(mprev, m1l);
                lsum = EXP2(mprev - msl) * lsum + EXP2(m1l - msl) * lx1[wg * 16 + l15];
                mprev = msl;
            }
        }
        if (grp == 0) {
            float rl[4];
#pragma unroll
            for (int r = 0; r < 4; ++r) rl[r] = 1.0f / __shfl(lsum, quad * 4 + r);
            const int orow = qt * 64 + wg * 16 + quad * 4;
#pragma unroll
            for (int dt = 0; dt < 4; ++dt)
#pragma unroll
                for (int r = 0; r < 4; ++r)
                    out[(long)(b * TT + orow + r) * HH + dt * 16 + l15] = o[dt][r] * rl[r];
        }
        __syncthreads();   // xchg/mx1 reusable by next phase
    };

    // ---------------- phase A: q-tile 63-p ----------------
    {
        const int qt = 63 - p;
        const int qrow = qt * 64 + wg * 16 + l15;
        const unsigned short* qbase = q_ws + (b * TT + qrow) * HH;
        const bf16x8 qf0 = *reinterpret_cast<const bf16x8*>(qbase + quad * 8);
        const bf16x8 qf1 = *reinterpret_cast<const bf16x8*>(qbase + 32 + quad * 8);
        f32x4 o[4];
#pragma unroll
        for (int dt = 0; dt < 4; ++dt) o[dt] = zero;
        float mprev = -1e30f, lsum = 0.f;
        run_phase(qt, qrow, qf0, qf1, o, mprev, lsum);
        merge_store(qt, o, mprev, lsum);
    }

    // ---------------- phase B: q-tile p ----------------
    {
        const int qt = p;
        const int qrow = qt * 64 + wg * 16 + l15;
        const unsigned short* qbase = q_ws + (b * TT + qrow) * HH;
        const bf16x8 qf0 = *reinterpret_cast<const bf16x8*>(qbase + quad * 8);
        const bf16x8 qf1 = *reinterpret_cast<const bf16x8*>(qbase + 32 + quad * 8);
        f32x4 o[4];
#pragma unroll
        for (int dt = 0; dt < 4; ++dt) o[dt] = zero;
        float mprev = -1e30f, lsum = 0.f;
        run_phase(qt, qrow, qf0, qf1, o, mprev, lsum);
        merge_store(qt, o, mprev, lsum);
    }
}

// ---------------------------------------------------------------- launch
extern "C" void kernel_launch(void* const* d_in, const int* in_sizes, int n_in,
                              void* d_out, int out_size, void* d_ws, size_t ws_size,
                              hipStream_t stream) {
    const float* x  = (const float*)d_in[0];
    const float* Wk = (const float*)d_in[1];
    const float* Wq = (const float*)d_in[2];
    const float* Wv = (const float*)d_in[3];
    float* out = (float*)d_out;

    char* ws = (char*)d_ws;
    unsigned short* Wt    = (unsigned short*)(ws);                         // 147456 B
    unsigned short* q_ws  = (unsigned short*)(ws + 147456);                // 4 MiB
    unsigned short* k_ws  = (unsigned short*)(ws + 147456 + 4194304);      // 4 MiB
    unsigned short* vt_ws = (unsigned short*)(ws + 147456 + 2 * 4194304);  // 4 MiB

    wtrans_kernel<<<dim3(6, 3), 256, 0, stream>>>(Wk, Wq, Wv, Wt);
    qkv_kernel<<<NROW / 32, 256, 0, stream>>>(x, Wt, q_ws, k_ws, vt_ws);
    attn_kernel<<<(TT / 128) * BB, 1024, 0, stream>>>(q_ws, k_ws, vt_ws, out);
}

// Round 8
// 272.158 us; speedup vs baseline: 1.1025x; 1.1025x over previous
//
#include <hip/hip_runtime.h>
#include <hip/hip_bf16.h>

// B=8, T=4096, C=384, H=64 causal single-head attention. fp32 in/out.
//
// Round-20: attn in-place K prefetch (no second buffer). Round-19
// post-mortem: kaA/kaB ping-pong needed ~170 live regs but a 1024-thread
// block hard-caps at 128 (16 waves resident only at >=4 waves/SIMD) ->
// spills (FETCH 348MB, WRITE 487MB, 4.6TB/s scratch traffic). Twice-learned
// rule: 1024-thr blocks must fit 128 regs. Fix: ka is dead right after the
// 8 QK MFMAs, so reload the SAME ka[8] in place: per tile
//   QK(ka) -> vb loads -> load_k(t+4, ka) -> softmax -> PV(vb).
// vmem queue = [vb(t).., ka(t+4)..]; compiler's counted vmcnt lets PV wait
// only on vb (vmcnt(8)) while ka(t+4) flies across softmax+PV (~600cy
// cover). Peak live ~118 < 128, zero extra buffers. qkv (r18 Wt pipeline),
// wtrans, all layouts unchanged.
// No-spill check: FETCH must be back at ~6.2MB. If spilled -> revert attn
// to r18. If clean but flat -> K latency exonerated; next: softmax VALU.
//
//  k_frag layout: [blk64][st][c8=h/8][i=m][j=h%8], row m of st holds
//                 K row s = 32*(st>>1) + 8*(m>>2) + 4*(st&1) + (m&3)
//  vt_frag layout: [st=row/64][dt=d/16][sc=s%64/8][i=d%16][j=s%8]

typedef __bf16 bf16x8 __attribute__((ext_vector_type(8)));
typedef float  f32x4  __attribute__((ext_vector_type(4)));

#define BB   8
#define TT   4096
#define CC   384
#define HH   64
#define NROW (BB*TT)       // 32768
// C^-0.5 * log2(e): fold softmax scale + exp2 conversion into q at projection
#define QSCALE (0.05103103630798288f * 1.4426950408889634f)

#if __has_builtin(__builtin_amdgcn_exp2f)
#define EXP2(x) __builtin_amdgcn_exp2f(x)
#else
#define EXP2(x) exp2f(x)
#endif

__device__ __forceinline__ unsigned short f2bf(float f) {
    __bf16 h = (__bf16)f;
    return __builtin_bit_cast(unsigned short, h);
}

// ---------------------------------------------------------------- kernel 1
// Wt[mat][h][c] = bf16(W[mat][c][h]), via LDS tile (coalesced both sides).
__global__ __launch_bounds__(256) void wtrans_kernel(
        const float* __restrict__ Wk,
        const float* __restrict__ Wq,
        const float* __restrict__ Wv,
        unsigned short* __restrict__ Wt) {
    __shared__ __align__(16) unsigned short tile[64][72];
    const float* Wm = (blockIdx.y == 0) ? Wk : ((blockIdx.y == 1) ? Wq : Wv);
    unsigned short* Wtm = Wt + blockIdx.y * (HH * CC);
    const int c0 = blockIdx.x * 64;
#pragma unroll
    for (int i = 0; i < 16; ++i) {
        int id = threadIdx.x + i * 256;         // 0..4095
        int c = id >> 6, h = id & 63;
        tile[c][h] = f2bf(Wm[(c0 + c) * HH + h]);   // coalesced read
    }
    __syncthreads();
#pragma unroll
    for (int i = 0; i < 16; ++i) {
        int id = threadIdx.x + i * 256;
        int h = id >> 6, c = id & 63;
        Wtm[h * CC + c0 + c] = tile[c][h];      // coalesced write
    }
}

// ---------------------------------------------------------------- kernel 2
// QKV projection: [32768,384]x[384,64] x3 with 16x16x32 bf16 MFMA.
// 1024 blocks x 256 thr; block = 32 rows. 4 waves = 2 row-tiles x 2 h-halves.
// ALL of x staged fp32 into LDS by 12 global_load_lds per wave (one vmcnt +
// one barrier). Wt consumed through a depth-12 register pipeline: bf[2][12],
// chunk kk+1 prefetched while chunk kk computes. k/q/vt epilogue layouts
// identical to round-15.
__global__ __launch_bounds__(256, 1) void qkv_kernel(
        const float* __restrict__ x,
        const unsigned short* __restrict__ Wt,     // [3][64][384] bf16
        unsigned short* __restrict__ q_ws,         // [32768][64] row-major, pre-scaled
        unsigned short* __restrict__ k_ws,         // fragment layout (permuted)
        unsigned short* __restrict__ vt_ws) {      // fragment layout
    // xs[chunk][local row][64 floats]; 16B slot p of (chunk,row) holds global
    // sub-chunk p ^ (row&7). 48 KB, chunk-major so each 1KB DMA instruction
    // (4 rows x 256B) is contiguous.
    __shared__ __align__(16) float xs[6][32][64];               // 49152 B
    __shared__ __align__(16) unsigned short vtile[64][40];      //  5120 B

    const int lane = threadIdx.x & 63;
    const int wv   = threadIdx.x >> 6;     // 0..3
    const int rt   = wv & 1;               // row-tile (16 rows)
    const int hh   = wv >> 1;              // h-half (2 nt)
    const int l15  = lane & 15;
    const int quad = lane >> 4;
    const int rb   = blockIdx.x * 32;
    const int ntb  = hh * 2;               // first of this wave's two nt

    // ---- stage ALL 6 chunks: 12 independent DMA instructions per wave ----
#pragma unroll
    for (int kk = 0; kk < 6; ++kk) {
#pragma unroll
        for (int j = 0; j < 2; ++j) {
            const int r0 = wv * 8 + j * 4;                 // instr's first row
            const int r  = r0 + quad;                      // this lane's row
            const int ch = l15 ^ (r & 7);                  // swizzled src chunk
            const float* src = x + (long)(rb + r) * CC + kk * 64 + ch * 4;
            float* dst = &xs[kk][r0][0];                   // linear: +lane*16B
            __builtin_amdgcn_global_load_lds(
                (const __attribute__((address_space(1))) unsigned int*)src,
                (__attribute__((address_space(3))) unsigned int*)dst,
                16, 0, 0);
        }
    }

    // ---- Wt register pipeline: 12 fragments per 64-col chunk ----
    bf16x8 bf[2][12];
    auto loadW = [&](int kk, bf16x8* dst) {
#pragma unroll
        for (int m = 0; m < 3; ++m)
#pragma unroll
            for (int n = 0; n < 2; ++n)
#pragma unroll
                for (int h01 = 0; h01 < 2; ++h01)
                    dst[m * 4 + n * 2 + h01] = *reinterpret_cast<const bf16x8*>(
                        Wt + m * (HH * CC) + ((ntb + n) * 16 + l15) * CC
                          + kk * 64 + h01 * 32 + quad * 8);
    };
    loadW(0, bf[0]);

    f32x4 acc[3][2];
    const f32x4 zero = {0.f, 0.f, 0.f, 0.f};
#pragma unroll
    for (int m = 0; m < 3; ++m)
#pragma unroll
        for (int n = 0; n < 2; ++n) acc[m][n] = zero;

    const int rloc = rt * 16 + l15;        // A-frag row (local)
    const int rx7  = rloc & 7;

    __asm volatile("s_waitcnt vmcnt(0)" ::: "memory");  // x DMA + bf[0]
    __syncthreads();

#pragma unroll
    for (int kk = 0; kk < 6; ++kk) {
        if (kk < 5) loadW(kk + 1, bf[(kk + 1) & 1]);   // 12 loads in flight
#pragma unroll
        for (int h01 = 0; h01 < 2; ++h01) {
            const int chb = 8 * h01 + 2 * quad;
            const f32x4 xa = *reinterpret_cast<const f32x4*>(
                &xs[kk][rloc][((chb) ^ rx7) * 4]);
            const f32x4 xb = *reinterpret_cast<const f32x4*>(
                &xs[kk][rloc][((chb + 1) ^ rx7) * 4]);
            bf16x8 a;
#pragma unroll
            for (int e = 0; e < 4; ++e) {
                a[e]     = (__bf16)xa[e];
                a[4 + e] = (__bf16)xb[e];
            }
#pragma unroll
            for (int m = 0; m < 3; ++m)
#pragma unroll
                for (int n = 0; n < 2; ++n)
                    acc[m][n] = __builtin_amdgcn_mfma_f32_16x16x32_bf16(
                        a, bf[kk & 1][m * 4 + n * 2 + h01], acc[m][n], 0, 0, 0);
        }
    }

    // Epilogue. C-layout: acc[m][n][r] = out[local row quad*4+r][h=(ntb+n)*16+l15]
#pragma unroll
    for (int n = 0; n < 2; ++n) {
        const int nt = ntb + n;
        const int h  = nt * 16 + l15;
        const int c8 = h >> 3;
        const int jj = h & 7;
#pragma unroll
        for (int r = 0; r < 4; ++r) {
            const int gr = rb + rt * 16 + quad * 4 + r;
            // k: permuted fragment position for local row s = gr & 63
            const int s   = gr & 63;
            const int stp = ((s >> 4) & 2) + ((s >> 2) & 1); // 2*(s>>5)+bit2
            const int ip  = ((s >> 1) & 12) + (s & 3);       // 4*((s>>3)&3)+(s&3)
            k_ws[(long)(gr >> 6) * 4096 + stp * 1024 + c8 * 128 + ip * 8 + jj]
                = f2bf(acc[0][n][r]);
            q_ws[gr * HH + h] = f2bf(acc[1][n][r] * QSCALE);
            vtile[h][rt * 16 + quad * 4 + r] = f2bf(acc[2][n][r]);
        }
    }
    __syncthreads();
    // vt fragment store: block covers sc-half (rb&32)>>3 of its 64-blk.
    {
        const int id  = threadIdx.x;               // 0..255
        const int dt  = id >> 6, scl = (id >> 4) & 3, ii = id & 15;
        const int sc  = scl + ((rb >> 3) & 4);
        unsigned short* dst = vt_ws + (long)(rb >> 6) * 4096
                              + (dt * 8 + sc) * 128 + ii * 8;
        *reinterpret_cast<uint4*>(dst) =
            *reinterpret_cast<const uint4*>(&vtile[dt * 16 + ii][scl * 8]);
    }
}

// ---------------------------------------------------------------- kernel 3
// Flash attention. 256 blocks x 1024 thr; block (p,b) does q-tile A=63-p
// then B=p (65 k-tiles constant). 16 waves = 4 groups x 4 waves; group g
// takes tiles t = 4j+g. Barrier-free k-loop, P entirely in registers;
// K stream prefetched IN PLACE (same ka[8] reloaded after QK consumes it;
// softmax+PV cover the latency); vb loaded before the prefetch so PV's
// counted vmcnt doesn't drain the ka loads.
__global__ __launch_bounds__(1024, 4) void attn_kernel(
        const unsigned short* __restrict__ q_ws,
        const unsigned short* __restrict__ k_ws,   // permuted fragment layout
        const unsigned short* __restrict__ vt_ws,  // fragment layout
        float* __restrict__ out) {
    __shared__ __align__(16) float xchg[64 * 65];                // 16640 B
    __shared__ float mx1[64], lx1[64];

    const int lane = threadIdx.x & 63;
    const int wv16 = threadIdx.x >> 6;     // 0..15
    const int grp  = wv16 >> 2;            // wave-group 0..3
    const int wg   = wv16 & 3;             // wave within group
    const int l15  = lane & 15;
    const int quad = lane >> 4;

    const int bid = blockIdx.x;
    const int b   = bid & 7;               // batch <-> XCD affinity
    const int p   = bid >> 3;              // 0..31

    const f32x4 zero = {0.f, 0.f, 0.f, 0.f};

    // -------- load the 8 K fragments of k-tile t into ka[0..7] --------
    auto load_k = [&](int t, bf16x8* ka) {
        const unsigned short* ktile = k_ws + ((long)((b * TT + t * 64) >> 4)) * 1024;
#pragma unroll
        for (int st = 0; st < 4; ++st) {
            ka[st]     = *reinterpret_cast<const bf16x8*>(
                ktile + ((st * 8 + quad) * 16 + l15) * 8);
            ka[4 + st] = *reinterpret_cast<const bf16x8*>(
                ktile + ((st * 8 + 4 + quad) * 16 + l15) * 8);
        }
    };

    // -------- run one phase: in-place prefetched k-loop --------
    auto run_phase = [&](int qt, int qrow,
                         const bf16x8& qf0, const bf16x8& qf1,
                         f32x4* o, float& mprev, float& lsum) {
        if (grp > qt) return;
        bf16x8 ka[8];
        load_k(grp, ka);
        for (int t = grp; t <= qt; t += 4) {
            const int s0 = t * 64;
            const unsigned short* vtile =
                vt_ws + ((long)((b * TT + s0) >> 6)) * 4096;

            // QK: consumes ka
            f32x4 sc[4];
#pragma unroll
            for (int st = 0; st < 4; ++st) {
                f32x4 z = zero;
                z = __builtin_amdgcn_mfma_f32_16x16x32_bf16(ka[st], qf0, z, 0, 0, 0);
                z = __builtin_amdgcn_mfma_f32_16x16x32_bf16(ka[4 + st], qf1, z, 0, 0, 0);
                sc[st] = z;
            }

            // vb loads first (older in vmem queue than the ka prefetch),
            // so PV's counted vmcnt leaves the ka loads in flight.
            bf16x8 vb0[4], vb1[4];
#pragma unroll
            for (int dt = 0; dt < 4; ++dt) {
                vb0[dt] = *reinterpret_cast<const bf16x8*>(
                    vtile + dt * 1024 + quad * 128 + l15 * 8);
                vb1[dt] = *reinterpret_cast<const bf16x8*>(
                    vtile + dt * 1024 + (4 + quad) * 128 + l15 * 8);
            }

            // in-place prefetch of next ka; cover = softmax + PV
            if (t + 4 <= qt) load_k(t + 4, ka);

            if (t == qt) {                // causal mask, diagonal tile only
                // permuted row map: s_local = 32*(st>>1)+8*quad+4*(st&1)+r
#pragma unroll
                for (int st = 0; st < 4; ++st)
#pragma unroll
                    for (int r = 0; r < 4; ++r) {
                        int sg = s0 + ((st >> 1) << 5) + (quad << 3)
                                   + ((st & 1) << 2) + r;
                        if (sg > qrow) sc[st][r] = -1e30f;
                    }
            }

            float mloc = -1e30f;
#pragma unroll
            for (int st = 0; st < 4; ++st)
#pragma unroll
                for (int r = 0; r < 4; ++r) mloc = fmaxf(mloc, sc[st][r]);
            mloc = fmaxf(mloc, __shfl_xor(mloc, 16));
            mloc = fmaxf(mloc, __shfl_xor(mloc, 32));
            const float mnew = fmaxf(mprev, mloc);
            const unsigned long long anych = __ballot(mnew > mprev);
            float alpha = 1.0f;
            if (anych) alpha = EXP2(mprev - mnew);

            float psum = 0.f;
#pragma unroll
            for (int st = 0; st < 4; ++st)
#pragma unroll
                for (int r = 0; r < 4; ++r) {
                    float pv = EXP2(sc[st][r] - mnew);
                    psum += pv;
                    sc[st][r] = pv;
                }
            psum += __shfl_xor(psum, 16);
            psum += __shfl_xor(psum, 32);
            lsum = lsum * alpha + psum;
            mprev = mnew;

            if (anych) {
                float ar[4];
#pragma unroll
                for (int r = 0; r < 4; ++r) ar[r] = __shfl(alpha, quad * 4 + r);
#pragma unroll
                for (int dt = 0; dt < 4; ++dt)
#pragma unroll
                    for (int r = 0; r < 4; ++r) o[dt][r] *= ar[r];
            }

            // P in-register: sc[st][r] already in PV A-fragment order.
            bf16x8 pf0, pf1;
#pragma unroll
            for (int r = 0; r < 4; ++r) {
                pf0[r]     = (__bf16)sc[0][r];
                pf0[4 + r] = (__bf16)sc[1][r];
                pf1[r]     = (__bf16)sc[2][r];
                pf1[4 + r] = (__bf16)sc[3][r];
            }
#pragma unroll
            for (int dt = 0; dt < 4; ++dt) {
                o[dt] = __builtin_amdgcn_mfma_f32_16x16x32_bf16(pf0, vb0[dt], o[dt], 0, 0, 0);
                o[dt] = __builtin_amdgcn_mfma_f32_16x16x32_bf16(pf1, vb1[dt], o[dt], 0, 0, 0);
            }
        }
    };

    // -------- merge groups 1..3 into group 0, then store q-tile `qt` --------
    auto merge_store = [&](int qt, f32x4* o, float& mprev, float& lsum) {
        for (int rr = 1; rr < 4; ++rr) {
            __syncthreads();
            if (grp == rr) {
                if (quad == 0) { mx1[wg * 16 + l15] = mprev; lx1[wg * 16 + l15] = lsum; }
#pragma unroll
                for (int dt = 0; dt < 4; ++dt)
#pragma unroll
                    for (int r = 0; r < 4; ++r)
                        xchg[(wg * 16 + quad * 4 + r) * 65 + dt * 16 + l15] = o[dt][r];
            }
            __syncthreads();
            if (grp == 0) {
#pragma unroll
                for (int r = 0; r < 4; ++r) {
                    const int row = wg * 16 + quad * 4 + r;
                    const float m0r = __shfl(mprev, quad * 4 + r);
                    const float m1r = mx1[row];
                    const float ms  = fmaxf(m0r, m1r);
                    const float w0  = EXP2(m0r - ms);
                    const float w1  = EXP2(m1r - ms);
#pragma unroll
                    for (int dt = 0; dt < 4; ++dt)
                        o[dt][r] = o[dt][r] * w0 + xchg[row * 65 + dt * 16 + l15] * w1;
                }
                const float m1l = mx1[wg * 16 + l15];
                const float msl = fmaxf(mprev, m1l);
                lsum = EXP2(mprev - msl) * lsum + EXP2(m1l - msl) * lx1[wg * 16 + l15];
                mprev = msl;
            }
        }
        if (grp == 0) {
            float rl[4];
#pragma unroll
            for (int r = 0; r < 4; ++r) rl[r] = 1.0f / __shfl(lsum, quad * 4 + r);
            const int orow = qt * 64 + wg * 16 + quad * 4;
#pragma unroll
            for (int dt = 0; dt < 4; ++dt)
#pragma unroll
                for (int r = 0; r < 4; ++r)
                    out[(long)(b * TT + orow + r) * HH + dt * 16 + l15] = o[dt][r] * rl[r];
        }
        __syncthreads();   // xchg/mx1 reusable by next phase
    };

    // ---------------- phase A: q-tile 63-p ----------------
    {
        const int qt = 63 - p;
        const int qrow = qt * 64 + wg * 16 + l15;
        const unsigned short* qbase = q_ws + (b * TT + qrow) * HH;
        const bf16x8 qf0 = *reinterpret_cast<const bf16x8*>(qbase + quad * 8);
        const bf16x8 qf1 = *reinterpret_cast<const bf16x8*>(qbase + 32 + quad * 8);
        f32x4 o[4];
#pragma unroll
        for (int dt = 0; dt < 4; ++dt) o[dt] = zero;
        float mprev = -1e30f, lsum = 0.f;
        run_phase(qt, qrow, qf0, qf1, o, mprev, lsum);
        merge_store(qt, o, mprev, lsum);
    }

    // ---------------- phase B: q-tile p ----------------
    {
        const int qt = p;
        const int qrow = qt * 64 + wg * 16 + l15;
        const unsigned short* qbase = q_ws + (b * TT + qrow) * HH;
        const bf16x8 qf0 = *reinterpret_cast<const bf16x8*>(qbase + quad * 8);
        const bf16x8 qf1 = *reinterpret_cast<const bf16x8*>(qbase + 32 + quad * 8);
        f32x4 o[4];
#pragma unroll
        for (int dt = 0; dt < 4; ++dt) o[dt] = zero;
        float mprev = -1e30f, lsum = 0.f;
        run_phase(qt, qrow, qf0, qf1, o, mprev, lsum);
        merge_store(qt, o, mprev, lsum);
    }
}

// ---------------------------------------------------------------- launch
extern "C" void kernel_launch(void* const* d_in, const int* in_sizes, int n_in,
                              void* d_out, int out_size, void* d_ws, size_t ws_size,
                              hipStream_t stream) {
    const float* x  = (const float*)d_in[0];
    const float* Wk = (const float*)d_in[1];
    const float* Wq = (const float*)d_in[2];
    const float* Wv = (const float*)d_in[3];
    float* out = (float*)d_out;

    char* ws = (char*)d_ws;
    unsigned short* Wt    = (unsigned short*)(ws);                         // 147456 B
    unsigned short* q_ws  = (unsigned short*)(ws + 147456);                // 4 MiB
    unsigned short* k_ws  = (unsigned short*)(ws + 147456 + 4194304);      // 4 MiB
    unsigned short* vt_ws = (unsigned short*)(ws + 147456 + 2 * 4194304);  // 4 MiB

    wtrans_kernel<<<dim3(6, 3), 256, 0, stream>>>(Wk, Wq, Wv, Wt);
    qkv_kernel<<<NROW / 32, 256, 0, stream>>>(x, Wt, q_ws, k_ws, vt_ws);
    attn_kernel<<<(TT / 128) * BB, 1024, 0, stream>>>(q_ws, k_ws, vt_ws, out);
}

// Round 9
// 161.004 us; speedup vs baseline: 1.8636x; 1.6904x over previous
//
#include <hip/hip_runtime.h>
#include <hip/hip_bf16.h>

// B=8, T=4096, C=384, H=64 causal single-head attention. fp32 in/out.
//
// Round-21: consolidate attn to r18 structure + zero-register softmax cuts.
// r19/r20 post-mortem: BOTH register-prefetch schemes spilled at VGPR=64 --
// the 128 unified regs/wave (16-wave block) hold arch+AGPR together; MFMA
// accumulators take ~64 AGPR side, leaving ~64 arch. r15-r18 fits exactly;
// any extra in-flight K state overflows -> scratch (r19: 487MB, r20: 417MB
// writes). Register K-prefetch in the 1024-thr structure is dead.
// This round, two chain-shrinking changes at +0 regs:
//  (1) defer-max (THR=8, exp2 domain): if __all(mloc <= mprev+8) keep the
//      old max -> skip alpha exp2 + 4 alpha-shfls + 16 o-mults. P bounded by
//      2^8=256 (bf16-safe; psum/lsum fp32-safe).
//  (2) lsum kept as per-quad partial (alpha is quad-uniform, recurrence is
//      linear) -> the 2-shfl quad reduction moves from per-tile to once at
//      merge entry.
// qkv (r18 Wt pipeline), wtrans, all layouts unchanged.
// No-spill gate: attn FETCH ~6.2MB, WRITE ~8MB, VGPR 64.
//
//  k_frag layout: [blk64][st][c8=h/8][i=m][j=h%8], row m of st holds
//                 K row s = 32*(st>>1) + 8*(m>>2) + 4*(st&1) + (m&3)
//  vt_frag layout: [st=row/64][dt=d/16][sc=s%64/8][i=d%16][j=s%8]

typedef __bf16 bf16x8 __attribute__((ext_vector_type(8)));
typedef float  f32x4  __attribute__((ext_vector_type(4)));

#define BB   8
#define TT   4096
#define CC   384
#define HH   64
#define NROW (BB*TT)       // 32768
// C^-0.5 * log2(e): fold softmax scale + exp2 conversion into q at projection
#define QSCALE (0.05103103630798288f * 1.4426950408889634f)

#if __has_builtin(__builtin_amdgcn_exp2f)
#define EXP2(x) __builtin_amdgcn_exp2f(x)
#else
#define EXP2(x) exp2f(x)
#endif

__device__ __forceinline__ unsigned short f2bf(float f) {
    __bf16 h = (__bf16)f;
    return __builtin_bit_cast(unsigned short, h);
}

// ---------------------------------------------------------------- kernel 1
// Wt[mat][h][c] = bf16(W[mat][c][h]), via LDS tile (coalesced both sides).
__global__ __launch_bounds__(256) void wtrans_kernel(
        const float* __restrict__ Wk,
        const float* __restrict__ Wq,
        const float* __restrict__ Wv,
        unsigned short* __restrict__ Wt) {
    __shared__ __align__(16) unsigned short tile[64][72];
    const float* Wm = (blockIdx.y == 0) ? Wk : ((blockIdx.y == 1) ? Wq : Wv);
    unsigned short* Wtm = Wt + blockIdx.y * (HH * CC);
    const int c0 = blockIdx.x * 64;
#pragma unroll
    for (int i = 0; i < 16; ++i) {
        int id = threadIdx.x + i * 256;         // 0..4095
        int c = id >> 6, h = id & 63;
        tile[c][h] = f2bf(Wm[(c0 + c) * HH + h]);   // coalesced read
    }
    __syncthreads();
#pragma unroll
    for (int i = 0; i < 16; ++i) {
        int id = threadIdx.x + i * 256;
        int h = id >> 6, c = id & 63;
        Wtm[h * CC + c0 + c] = tile[c][h];      // coalesced write
    }
}

// ---------------------------------------------------------------- kernel 2
// QKV projection: [32768,384]x[384,64] x3 with 16x16x32 bf16 MFMA.
// 1024 blocks x 256 thr; block = 32 rows. 4 waves = 2 row-tiles x 2 h-halves.
// ALL of x staged fp32 into LDS by 12 global_load_lds per wave (one vmcnt +
// one barrier). Wt consumed through a depth-12 register pipeline: bf[2][12],
// chunk kk+1 prefetched while chunk kk computes. k/q/vt epilogue layouts
// identical to round-15.
__global__ __launch_bounds__(256, 1) void qkv_kernel(
        const float* __restrict__ x,
        const unsigned short* __restrict__ Wt,     // [3][64][384] bf16
        unsigned short* __restrict__ q_ws,         // [32768][64] row-major, pre-scaled
        unsigned short* __restrict__ k_ws,         // fragment layout (permuted)
        unsigned short* __restrict__ vt_ws) {      // fragment layout
    // xs[chunk][local row][64 floats]; 16B slot p of (chunk,row) holds global
    // sub-chunk p ^ (row&7). 48 KB, chunk-major so each 1KB DMA instruction
    // (4 rows x 256B) is contiguous.
    __shared__ __align__(16) float xs[6][32][64];               // 49152 B
    __shared__ __align__(16) unsigned short vtile[64][40];      //  5120 B

    const int lane = threadIdx.x & 63;
    const int wv   = threadIdx.x >> 6;     // 0..3
    const int rt   = wv & 1;               // row-tile (16 rows)
    const int hh   = wv >> 1;              // h-half (2 nt)
    const int l15  = lane & 15;
    const int quad = lane >> 4;
    const int rb   = blockIdx.x * 32;
    const int ntb  = hh * 2;               // first of this wave's two nt

    // ---- stage ALL 6 chunks: 12 independent DMA instructions per wave ----
#pragma unroll
    for (int kk = 0; kk < 6; ++kk) {
#pragma unroll
        for (int j = 0; j < 2; ++j) {
            const int r0 = wv * 8 + j * 4;                 // instr's first row
            const int r  = r0 + quad;                      // this lane's row
            const int ch = l15 ^ (r & 7);                  // swizzled src chunk
            const float* src = x + (long)(rb + r) * CC + kk * 64 + ch * 4;
            float* dst = &xs[kk][r0][0];                   // linear: +lane*16B
            __builtin_amdgcn_global_load_lds(
                (const __attribute__((address_space(1))) unsigned int*)src,
                (__attribute__((address_space(3))) unsigned int*)dst,
                16, 0, 0);
        }
    }

    // ---- Wt register pipeline: 12 fragments per 64-col chunk ----
    bf16x8 bf[2][12];
    auto loadW = [&](int kk, bf16x8* dst) {
#pragma unroll
        for (int m = 0; m < 3; ++m)
#pragma unroll
            for (int n = 0; n < 2; ++n)
#pragma unroll
                for (int h01 = 0; h01 < 2; ++h01)
                    dst[m * 4 + n * 2 + h01] = *reinterpret_cast<const bf16x8*>(
                        Wt + m * (HH * CC) + ((ntb + n) * 16 + l15) * CC
                          + kk * 64 + h01 * 32 + quad * 8);
    };
    loadW(0, bf[0]);

    f32x4 acc[3][2];
    const f32x4 zero = {0.f, 0.f, 0.f, 0.f};
#pragma unroll
    for (int m = 0; m < 3; ++m)
#pragma unroll
        for (int n = 0; n < 2; ++n) acc[m][n] = zero;

    const int rloc = rt * 16 + l15;        // A-frag row (local)
    const int rx7  = rloc & 7;

    __asm volatile("s_waitcnt vmcnt(0)" ::: "memory");  // x DMA + bf[0]
    __syncthreads();

#pragma unroll
    for (int kk = 0; kk < 6; ++kk) {
        if (kk < 5) loadW(kk + 1, bf[(kk + 1) & 1]);   // 12 loads in flight
#pragma unroll
        for (int h01 = 0; h01 < 2; ++h01) {
            const int chb = 8 * h01 + 2 * quad;
            const f32x4 xa = *reinterpret_cast<const f32x4*>(
                &xs[kk][rloc][((chb) ^ rx7) * 4]);
            const f32x4 xb = *reinterpret_cast<const f32x4*>(
                &xs[kk][rloc][((chb + 1) ^ rx7) * 4]);
            bf16x8 a;
#pragma unroll
            for (int e = 0; e < 4; ++e) {
                a[e]     = (__bf16)xa[e];
                a[4 + e] = (__bf16)xb[e];
            }
#pragma unroll
            for (int m = 0; m < 3; ++m)
#pragma unroll
                for (int n = 0; n < 2; ++n)
                    acc[m][n] = __builtin_amdgcn_mfma_f32_16x16x32_bf16(
                        a, bf[kk & 1][m * 4 + n * 2 + h01], acc[m][n], 0, 0, 0);
        }
    }

    // Epilogue. C-layout: acc[m][n][r] = out[local row quad*4+r][h=(ntb+n)*16+l15]
#pragma unroll
    for (int n = 0; n < 2; ++n) {
        const int nt = ntb + n;
        const int h  = nt * 16 + l15;
        const int c8 = h >> 3;
        const int jj = h & 7;
#pragma unroll
        for (int r = 0; r < 4; ++r) {
            const int gr = rb + rt * 16 + quad * 4 + r;
            // k: permuted fragment position for local row s = gr & 63
            const int s   = gr & 63;
            const int stp = ((s >> 4) & 2) + ((s >> 2) & 1); // 2*(s>>5)+bit2
            const int ip  = ((s >> 1) & 12) + (s & 3);       // 4*((s>>3)&3)+(s&3)
            k_ws[(long)(gr >> 6) * 4096 + stp * 1024 + c8 * 128 + ip * 8 + jj]
                = f2bf(acc[0][n][r]);
            q_ws[gr * HH + h] = f2bf(acc[1][n][r] * QSCALE);
            vtile[h][rt * 16 + quad * 4 + r] = f2bf(acc[2][n][r]);
        }
    }
    __syncthreads();
    // vt fragment store: block covers sc-half (rb&32)>>3 of its 64-blk.
    {
        const int id  = threadIdx.x;               // 0..255
        const int dt  = id >> 6, scl = (id >> 4) & 3, ii = id & 15;
        const int sc  = scl + ((rb >> 3) & 4);
        unsigned short* dst = vt_ws + (long)(rb >> 6) * 4096
                              + (dt * 8 + sc) * 128 + ii * 8;
        *reinterpret_cast<uint4*>(dst) =
            *reinterpret_cast<const uint4*>(&vtile[dt * 16 + ii][scl * 8]);
    }
}

// ---------------------------------------------------------------- kernel 3
// Flash attention. 256 blocks x 1024 thr; block (p,b) does q-tile A=63-p
// then B=p (65 k-tiles constant). 16 waves = 4 groups x 4 waves; group g
// takes tiles t = 4j+g. Barrier-free k-loop, P entirely in registers
// (k_frag row permutation makes QK output == PV A-fragment).
// Softmax: defer-max (THR=8) skips rescale most tiles; lsum kept per-quad,
// reduced once at merge entry.
__global__ __launch_bounds__(1024, 4) void attn_kernel(
        const unsigned short* __restrict__ q_ws,
        const unsigned short* __restrict__ k_ws,   // permuted fragment layout
        const unsigned short* __restrict__ vt_ws,  // fragment layout
        float* __restrict__ out) {
    __shared__ __align__(16) float xchg[64 * 65];                // 16640 B
    __shared__ float mx1[64], lx1[64];

    const int lane = threadIdx.x & 63;
    const int wv16 = threadIdx.x >> 6;     // 0..15
    const int grp  = wv16 >> 2;            // wave-group 0..3
    const int wg   = wv16 & 3;             // wave within group
    const int l15  = lane & 15;
    const int quad = lane >> 4;

    const int bid = blockIdx.x;
    const int b   = bid & 7;               // batch <-> XCD affinity
    const int p   = bid >> 3;              // 0..31

    const f32x4 zero = {0.f, 0.f, 0.f, 0.f};

    // -------- one k-tile of phase with q-tile `qt` --------
    auto do_tile = [&](int t, int qt, int qrow,
                       const bf16x8& qf0, const bf16x8& qf1,
                       f32x4* o, float& mprev, float& lsum) {
        const int s0 = t * 64;
        const unsigned short* ktile = k_ws + ((long)((b * TT + s0) >> 4)) * 1024;
        const unsigned short* vtile = vt_ws + ((long)((b * TT + s0) >> 6)) * 4096;

        bf16x8 ka0[4], ka1[4];
#pragma unroll
        for (int st = 0; st < 4; ++st) {
            ka0[st] = *reinterpret_cast<const bf16x8*>(
                ktile + ((st * 8 + quad) * 16 + l15) * 8);
            ka1[st] = *reinterpret_cast<const bf16x8*>(
                ktile + ((st * 8 + 4 + quad) * 16 + l15) * 8);
        }
        bf16x8 vb0[4], vb1[4];
#pragma unroll
        for (int dt = 0; dt < 4; ++dt) {
            vb0[dt] = *reinterpret_cast<const bf16x8*>(
                vtile + dt * 1024 + quad * 128 + l15 * 8);
            vb1[dt] = *reinterpret_cast<const bf16x8*>(
                vtile + dt * 1024 + (4 + quad) * 128 + l15 * 8);
        }

        f32x4 sc[4];
#pragma unroll
        for (int st = 0; st < 4; ++st) {
            f32x4 z = zero;
            z = __builtin_amdgcn_mfma_f32_16x16x32_bf16(ka0[st], qf0, z, 0, 0, 0);
            z = __builtin_amdgcn_mfma_f32_16x16x32_bf16(ka1[st], qf1, z, 0, 0, 0);
            sc[st] = z;
        }

        if (t == qt) {                    // causal mask, diagonal tile only
            // permuted row map: s_local = 32*(st>>1) + 8*quad + 4*(st&1) + r
#pragma unroll
            for (int st = 0; st < 4; ++st)
#pragma unroll
                for (int r = 0; r < 4; ++r) {
                    int sg = s0 + ((st >> 1) << 5) + (quad << 3)
                               + ((st & 1) << 2) + r;
                    if (sg > qrow) sc[st][r] = -1e30f;
                }
        }

        float mloc = -1e30f;
#pragma unroll
        for (int st = 0; st < 4; ++st)
#pragma unroll
            for (int r = 0; r < 4; ++r) mloc = fmaxf(mloc, sc[st][r]);
        mloc = fmaxf(mloc, __shfl_xor(mloc, 16));
        mloc = fmaxf(mloc, __shfl_xor(mloc, 32));

        // defer-max: keep old max when the tile max is within THR=8
        // (exp2 domain; P bounded by 2^8=256, bf16/fp32-safe).
        if (!__all(mloc <= mprev + 8.0f)) {
            const float mnew = fmaxf(mprev, mloc);
            const float alpha = EXP2(mprev - mnew);
            lsum *= alpha;
            float ar[4];
#pragma unroll
            for (int r = 0; r < 4; ++r) ar[r] = __shfl(alpha, quad * 4 + r);
#pragma unroll
            for (int dt = 0; dt < 4; ++dt)
#pragma unroll
                for (int r = 0; r < 4; ++r) o[dt][r] *= ar[r];
            mprev = mnew;
        }

        // exp2 against (possibly stale) mprev; lsum stays per-quad partial.
        float psum = 0.f;
#pragma unroll
        for (int st = 0; st < 4; ++st)
#pragma unroll
            for (int r = 0; r < 4; ++r) {
                float pv = EXP2(sc[st][r] - mprev);
                psum += pv;
                sc[st][r] = pv;
            }
        lsum += psum;

        // P in-register: sc[st][r] already in PV A-fragment order.
        bf16x8 pf0, pf1;
#pragma unroll
        for (int r = 0; r < 4; ++r) {
            pf0[r]     = (__bf16)sc[0][r];
            pf0[4 + r] = (__bf16)sc[1][r];
            pf1[r]     = (__bf16)sc[2][r];
            pf1[4 + r] = (__bf16)sc[3][r];
        }
#pragma unroll
        for (int dt = 0; dt < 4; ++dt) {
            o[dt] = __builtin_amdgcn_mfma_f32_16x16x32_bf16(pf0, vb0[dt], o[dt], 0, 0, 0);
            o[dt] = __builtin_amdgcn_mfma_f32_16x16x32_bf16(pf1, vb1[dt], o[dt], 0, 0, 0);
        }
    };

    // -------- merge groups 1..3 into group 0, then store q-tile `qt` --------
    auto merge_store = [&](int qt, f32x4* o, float& mprev, float& lsum) {
        // complete the deferred quad-reduction of lsum (once per phase)
        lsum += __shfl_xor(lsum, 16);
        lsum += __shfl_xor(lsum, 32);
        for (int rr = 1; rr < 4; ++rr) {
            __syncthreads();
            if (grp == rr) {
                if (quad == 0) { mx1[wg * 16 + l15] = mprev; lx1[wg * 16 + l15] = lsum; }
#pragma unroll
                for (int dt = 0; dt < 4; ++dt)
#pragma unroll
                    for (int r = 0; r < 4; ++r)
                        xchg[(wg * 16 + quad * 4 + r) * 65 + dt * 16 + l15] = o[dt][r];
            }
            __syncthreads();
            if (grp == 0) {
#pragma unroll
                for (int r = 0; r < 4; ++r) {
                    const int row = wg * 16 + quad * 4 + r;
                    const float m0r = __shfl(mprev, quad * 4 + r);
                    const float m1r = mx1[row];
                    const float ms  = fmaxf(m0r, m1r);
                    const float w0  = EXP2(m0r - ms);
                    const float w1  = EXP2(m1r - ms);
#pragma unroll
                    for (int dt = 0; dt < 4; ++dt)
                        o[dt][r] = o[dt][r] * w0 + xchg[row * 65 + dt * 16 + l15] * w1;
                }
                const float m1l = mx1[wg * 16 + l15];
                const float msl = fmaxf(mprev, m1l);
                lsum = EXP2(mprev - msl) * lsum + EXP2(m1l - msl) * lx1[wg * 16 + l15];
                mprev = msl;
            }
        }
        if (grp == 0) {
            float rl[4];
#pragma unroll
            for (int r = 0; r < 4; ++r) rl[r] = 1.0f / __shfl(lsum, quad * 4 + r);
            const int orow = qt * 64 + wg * 16 + quad * 4;
#pragma unroll
            for (int dt = 0; dt < 4; ++dt)
#pragma unroll
                for (int r = 0; r < 4; ++r)
                    out[(long)(b * TT + orow + r) * HH + dt * 16 + l15] = o[dt][r] * rl[r];
        }
        __syncthreads();   // xchg/mx1 reusable by next phase
    };

    // ---------------- phase A: q-tile 63-p ----------------
    {
        const int qt = 63 - p;
        const int qrow = qt * 64 + wg * 16 + l15;
        const unsigned short* qbase = q_ws + (b * TT + qrow) * HH;
        const bf16x8 qf0 = *reinterpret_cast<const bf16x8*>(qbase + quad * 8);
        const bf16x8 qf1 = *reinterpret_cast<const bf16x8*>(qbase + 32 + quad * 8);
        f32x4 o[4];
#pragma unroll
        for (int dt = 0; dt < 4; ++dt) o[dt] = zero;
        float mprev = -1e30f, lsum = 0.f;
        for (int t = grp; t <= qt; t += 4)
            do_tile(t, qt, qrow, qf0, qf1, o, mprev, lsum);
        merge_store(qt, o, mprev, lsum);
    }

    // ---------------- phase B: q-tile p ----------------
    {
        const int qt = p;
        const int qrow = qt * 64 + wg * 16 + l15;
        const unsigned short* qbase = q_ws + (b * TT + qrow) * HH;
        const bf16x8 qf0 = *reinterpret_cast<const bf16x8*>(qbase + quad * 8);
        const bf16x8 qf1 = *reinterpret_cast<const bf16x8*>(qbase + 32 + quad * 8);
        f32x4 o[4];
#pragma unroll
        for (int dt = 0; dt < 4; ++dt) o[dt] = zero;
        float mprev = -1e30f, lsum = 0.f;
        for (int t = grp; t <= qt; t += 4)
            do_tile(t, qt, qrow, qf0, qf1, o, mprev, lsum);
        merge_store(qt, o, mprev, lsum);
    }
}

// ---------------------------------------------------------------- launch
extern "C" void kernel_launch(void* const* d_in, const int* in_sizes, int n_in,
                              void* d_out, int out_size, void* d_ws, size_t ws_size,
                              hipStream_t stream) {
    const float* x  = (const float*)d_in[0];
    const float* Wk = (const float*)d_in[1];
    const float* Wq = (const float*)d_in[2];
    const float* Wv = (const float*)d_in[3];
    float* out = (float*)d_out;

    char* ws = (char*)d_ws;
    unsigned short* Wt    = (unsigned short*)(ws);                         // 147456 B
    unsigned short* q_ws  = (unsigned short*)(ws + 147456);                // 4 MiB
    unsigned short* k_ws  = (unsigned short*)(ws + 147456 + 4194304);      // 4 MiB
    unsigned short* vt_ws = (unsigned short*)(ws + 147456 + 2 * 4194304);  // 4 MiB

    wtrans_kernel<<<dim3(6, 3), 256, 0, stream>>>(Wk, Wq, Wv, Wt);
    qkv_kernel<<<NROW / 32, 256, 0, stream>>>(x, Wt, q_ws, k_ws, vt_ws);
    attn_kernel<<<(TT / 128) * BB, 1024, 0, stream>>>(q_ws, k_ws, vt_ws, out);
}

// Round 10
// 160.452 us; speedup vs baseline: 1.8700x; 1.0034x over previous
//
#include <hip/hip_runtime.h>
#include <hip/hip_bf16.h>

// B=8, T=4096, C=384, H=64 causal single-head attention. fp32 in/out.
//
// Round-22: two independent zero-risk levers.
// r21 post-mortem: attn improved to 45.2us (defer-max + deferred lsum, no
// spill). NEW FACT: qkv reappeared in top-5 at 46.9us with VGPR=68 -> the
// r18 Wt register pipeline NEVER codegen'd (needs ~96 arch regs; compiler's
// pressure heuristic sank the loads back to their uses; launch_bounds alone
// doesn't override the scheduler). r18's "win" was a top-5 table artifact.
//  (1) qkv: asm volatile("" ::: "memory") after each loadW(kk+1) -- memory
//      ops can't cross an asm memory clobber, so the 12 Wt loads must ISSUE
//      before chunk kk's ds_reads/MFMAs; their waitcnt lands at chunk kk+1's
//      MFMAs with counted vmcnt. Gate: VGPR must jump to ~140-160.
//  (2) attn: s_setprio(1) around QK and PV MFMA clusters (T5) -- barrier-
//      free k-loop = waves at independent phases, the measured +4-7% regime.
// Everything else byte-identical to r21.
//
//  k_frag layout: [blk64][st][c8=h/8][i=m][j=h%8], row m of st holds
//                 K row s = 32*(st>>1) + 8*(m>>2) + 4*(st&1) + (m&3)
//  vt_frag layout: [st=row/64][dt=d/16][sc=s%64/8][i=d%16][j=s%8]

typedef __bf16 bf16x8 __attribute__((ext_vector_type(8)));
typedef float  f32x4  __attribute__((ext_vector_type(4)));

#define BB   8
#define TT   4096
#define CC   384
#define HH   64
#define NROW (BB*TT)       // 32768
// C^-0.5 * log2(e): fold softmax scale + exp2 conversion into q at projection
#define QSCALE (0.05103103630798288f * 1.4426950408889634f)

#if __has_builtin(__builtin_amdgcn_exp2f)
#define EXP2(x) __builtin_amdgcn_exp2f(x)
#else
#define EXP2(x) exp2f(x)
#endif

__device__ __forceinline__ unsigned short f2bf(float f) {
    __bf16 h = (__bf16)f;
    return __builtin_bit_cast(unsigned short, h);
}

// ---------------------------------------------------------------- kernel 1
// Wt[mat][h][c] = bf16(W[mat][c][h]), via LDS tile (coalesced both sides).
__global__ __launch_bounds__(256) void wtrans_kernel(
        const float* __restrict__ Wk,
        const float* __restrict__ Wq,
        const float* __restrict__ Wv,
        unsigned short* __restrict__ Wt) {
    __shared__ __align__(16) unsigned short tile[64][72];
    const float* Wm = (blockIdx.y == 0) ? Wk : ((blockIdx.y == 1) ? Wq : Wv);
    unsigned short* Wtm = Wt + blockIdx.y * (HH * CC);
    const int c0 = blockIdx.x * 64;
#pragma unroll
    for (int i = 0; i < 16; ++i) {
        int id = threadIdx.x + i * 256;         // 0..4095
        int c = id >> 6, h = id & 63;
        tile[c][h] = f2bf(Wm[(c0 + c) * HH + h]);   // coalesced read
    }
    __syncthreads();
#pragma unroll
    for (int i = 0; i < 16; ++i) {
        int id = threadIdx.x + i * 256;
        int h = id >> 6, c = id & 63;
        Wtm[h * CC + c0 + c] = tile[c][h];      // coalesced write
    }
}

// ---------------------------------------------------------------- kernel 2
// QKV projection: [32768,384]x[384,64] x3 with 16x16x32 bf16 MFMA.
// 1024 blocks x 256 thr; block = 32 rows. 4 waves = 2 row-tiles x 2 h-halves.
// ALL of x staged fp32 into LDS by 12 global_load_lds per wave (one vmcnt +
// one barrier). Wt consumed through a depth-12 register pipeline: bf[2][12],
// chunk kk+1 prefetched while chunk kk computes; an asm memory fence after
// each prefetch pins the loads at issue position (scheduler can't sink them).
__global__ __launch_bounds__(256, 1) void qkv_kernel(
        const float* __restrict__ x,
        const unsigned short* __restrict__ Wt,     // [3][64][384] bf16
        unsigned short* __restrict__ q_ws,         // [32768][64] row-major, pre-scaled
        unsigned short* __restrict__ k_ws,         // fragment layout (permuted)
        unsigned short* __restrict__ vt_ws) {      // fragment layout
    // xs[chunk][local row][64 floats]; 16B slot p of (chunk,row) holds global
    // sub-chunk p ^ (row&7). 48 KB, chunk-major so each 1KB DMA instruction
    // (4 rows x 256B) is contiguous.
    __shared__ __align__(16) float xs[6][32][64];               // 49152 B
    __shared__ __align__(16) unsigned short vtile[64][40];      //  5120 B

    const int lane = threadIdx.x & 63;
    const int wv   = threadIdx.x >> 6;     // 0..3
    const int rt   = wv & 1;               // row-tile (16 rows)
    const int hh   = wv >> 1;              // h-half (2 nt)
    const int l15  = lane & 15;
    const int quad = lane >> 4;
    const int rb   = blockIdx.x * 32;
    const int ntb  = hh * 2;               // first of this wave's two nt

    // ---- stage ALL 6 chunks: 12 independent DMA instructions per wave ----
#pragma unroll
    for (int kk = 0; kk < 6; ++kk) {
#pragma unroll
        for (int j = 0; j < 2; ++j) {
            const int r0 = wv * 8 + j * 4;                 // instr's first row
            const int r  = r0 + quad;                      // this lane's row
            const int ch = l15 ^ (r & 7);                  // swizzled src chunk
            const float* src = x + (long)(rb + r) * CC + kk * 64 + ch * 4;
            float* dst = &xs[kk][r0][0];                   // linear: +lane*16B
            __builtin_amdgcn_global_load_lds(
                (const __attribute__((address_space(1))) unsigned int*)src,
                (__attribute__((address_space(3))) unsigned int*)dst,
                16, 0, 0);
        }
    }

    // ---- Wt register pipeline: 12 fragments per 64-col chunk ----
    bf16x8 bf[2][12];
    auto loadW = [&](int kk, bf16x8* dst) {
#pragma unroll
        for (int m = 0; m < 3; ++m)
#pragma unroll
            for (int n = 0; n < 2; ++n)
#pragma unroll
                for (int h01 = 0; h01 < 2; ++h01)
                    dst[m * 4 + n * 2 + h01] = *reinterpret_cast<const bf16x8*>(
                        Wt + m * (HH * CC) + ((ntb + n) * 16 + l15) * CC
                          + kk * 64 + h01 * 32 + quad * 8);
    };
    loadW(0, bf[0]);

    f32x4 acc[3][2];
    const f32x4 zero = {0.f, 0.f, 0.f, 0.f};
#pragma unroll
    for (int m = 0; m < 3; ++m)
#pragma unroll
        for (int n = 0; n < 2; ++n) acc[m][n] = zero;

    const int rloc = rt * 16 + l15;        // A-frag row (local)
    const int rx7  = rloc & 7;

    __asm volatile("s_waitcnt vmcnt(0)" ::: "memory");  // x DMA + bf[0]
    __syncthreads();

#pragma unroll
    for (int kk = 0; kk < 6; ++kk) {
        if (kk < 5) {
            loadW(kk + 1, bf[(kk + 1) & 1]);   // 12 loads in flight
            // pin the prefetch at issue position: memory ops cannot cross
            // an asm memory clobber, so the scheduler can't sink these 12
            // loads down to their uses in the next chunk.
            __asm volatile("" ::: "memory");
        }
#pragma unroll
        for (int h01 = 0; h01 < 2; ++h01) {
            const int chb = 8 * h01 + 2 * quad;
            const f32x4 xa = *reinterpret_cast<const f32x4*>(
                &xs[kk][rloc][((chb) ^ rx7) * 4]);
            const f32x4 xb = *reinterpret_cast<const f32x4*>(
                &xs[kk][rloc][((chb + 1) ^ rx7) * 4]);
            bf16x8 a;
#pragma unroll
            for (int e = 0; e < 4; ++e) {
                a[e]     = (__bf16)xa[e];
                a[4 + e] = (__bf16)xb[e];
            }
#pragma unroll
            for (int m = 0; m < 3; ++m)
#pragma unroll
                for (int n = 0; n < 2; ++n)
                    acc[m][n] = __builtin_amdgcn_mfma_f32_16x16x32_bf16(
                        a, bf[kk & 1][m * 4 + n * 2 + h01], acc[m][n], 0, 0, 0);
        }
    }

    // Epilogue. C-layout: acc[m][n][r] = out[local row quad*4+r][h=(ntb+n)*16+l15]
#pragma unroll
    for (int n = 0; n < 2; ++n) {
        const int nt = ntb + n;
        const int h  = nt * 16 + l15;
        const int c8 = h >> 3;
        const int jj = h & 7;
#pragma unroll
        for (int r = 0; r < 4; ++r) {
            const int gr = rb + rt * 16 + quad * 4 + r;
            // k: permuted fragment position for local row s = gr & 63
            const int s   = gr & 63;
            const int stp = ((s >> 4) & 2) + ((s >> 2) & 1); // 2*(s>>5)+bit2
            const int ip  = ((s >> 1) & 12) + (s & 3);       // 4*((s>>3)&3)+(s&3)
            k_ws[(long)(gr >> 6) * 4096 + stp * 1024 + c8 * 128 + ip * 8 + jj]
                = f2bf(acc[0][n][r]);
            q_ws[gr * HH + h] = f2bf(acc[1][n][r] * QSCALE);
            vtile[h][rt * 16 + quad * 4 + r] = f2bf(acc[2][n][r]);
        }
    }
    __syncthreads();
    // vt fragment store: block covers sc-half (rb&32)>>3 of its 64-blk.
    {
        const int id  = threadIdx.x;               // 0..255
        const int dt  = id >> 6, scl = (id >> 4) & 3, ii = id & 15;
        const int sc  = scl + ((rb >> 3) & 4);
        unsigned short* dst = vt_ws + (long)(rb >> 6) * 4096
                              + (dt * 8 + sc) * 128 + ii * 8;
        *reinterpret_cast<uint4*>(dst) =
            *reinterpret_cast<const uint4*>(&vtile[dt * 16 + ii][scl * 8]);
    }
}

// ---------------------------------------------------------------- kernel 3
// Flash attention. 256 blocks x 1024 thr; block (p,b) does q-tile A=63-p
// then B=p (65 k-tiles constant). 16 waves = 4 groups x 4 waves; group g
// takes tiles t = 4j+g. Barrier-free k-loop, P entirely in registers
// (k_frag row permutation makes QK output == PV A-fragment).
// Softmax: defer-max (THR=8); lsum per-quad, reduced at merge entry.
// s_setprio(1) around QK/PV MFMA clusters (waves at independent phases).
__global__ __launch_bounds__(1024, 4) void attn_kernel(
        const unsigned short* __restrict__ q_ws,
        const unsigned short* __restrict__ k_ws,   // permuted fragment layout
        const unsigned short* __restrict__ vt_ws,  // fragment layout
        float* __restrict__ out) {
    __shared__ __align__(16) float xchg[64 * 65];                // 16640 B
    __shared__ float mx1[64], lx1[64];

    const int lane = threadIdx.x & 63;
    const int wv16 = threadIdx.x >> 6;     // 0..15
    const int grp  = wv16 >> 2;            // wave-group 0..3
    const int wg   = wv16 & 3;             // wave within group
    const int l15  = lane & 15;
    const int quad = lane >> 4;

    const int bid = blockIdx.x;
    const int b   = bid & 7;               // batch <-> XCD affinity
    const int p   = bid >> 3;              // 0..31

    const f32x4 zero = {0.f, 0.f, 0.f, 0.f};

    // -------- one k-tile of phase with q-tile `qt` --------
    auto do_tile = [&](int t, int qt, int qrow,
                       const bf16x8& qf0, const bf16x8& qf1,
                       f32x4* o, float& mprev, float& lsum) {
        const int s0 = t * 64;
        const unsigned short* ktile = k_ws + ((long)((b * TT + s0) >> 4)) * 1024;
        const unsigned short* vtile = vt_ws + ((long)((b * TT + s0) >> 6)) * 4096;

        bf16x8 ka0[4], ka1[4];
#pragma unroll
        for (int st = 0; st < 4; ++st) {
            ka0[st] = *reinterpret_cast<const bf16x8*>(
                ktile + ((st * 8 + quad) * 16 + l15) * 8);
            ka1[st] = *reinterpret_cast<const bf16x8*>(
                ktile + ((st * 8 + 4 + quad) * 16 + l15) * 8);
        }
        bf16x8 vb0[4], vb1[4];
#pragma unroll
        for (int dt = 0; dt < 4; ++dt) {
            vb0[dt] = *reinterpret_cast<const bf16x8*>(
                vtile + dt * 1024 + quad * 128 + l15 * 8);
            vb1[dt] = *reinterpret_cast<const bf16x8*>(
                vtile + dt * 1024 + (4 + quad) * 128 + l15 * 8);
        }

        f32x4 sc[4];
        __builtin_amdgcn_s_setprio(1);
#pragma unroll
        for (int st = 0; st < 4; ++st) {
            f32x4 z = zero;
            z = __builtin_amdgcn_mfma_f32_16x16x32_bf16(ka0[st], qf0, z, 0, 0, 0);
            z = __builtin_amdgcn_mfma_f32_16x16x32_bf16(ka1[st], qf1, z, 0, 0, 0);
            sc[st] = z;
        }
        __builtin_amdgcn_s_setprio(0);

        if (t == qt) {                    // causal mask, diagonal tile only
            // permuted row map: s_local = 32*(st>>1) + 8*quad + 4*(st&1) + r
#pragma unroll
            for (int st = 0; st < 4; ++st)
#pragma unroll
                for (int r = 0; r < 4; ++r) {
                    int sg = s0 + ((st >> 1) << 5) + (quad << 3)
                               + ((st & 1) << 2) + r;
                    if (sg > qrow) sc[st][r] = -1e30f;
                }
        }

        float mloc = -1e30f;
#pragma unroll
        for (int st = 0; st < 4; ++st)
#pragma unroll
            for (int r = 0; r < 4; ++r) mloc = fmaxf(mloc, sc[st][r]);
        mloc = fmaxf(mloc, __shfl_xor(mloc, 16));
        mloc = fmaxf(mloc, __shfl_xor(mloc, 32));

        // defer-max: keep old max when the tile max is within THR=8
        // (exp2 domain; P bounded by 2^8=256, bf16/fp32-safe).
        if (!__all(mloc <= mprev + 8.0f)) {
            const float mnew = fmaxf(mprev, mloc);
            const float alpha = EXP2(mprev - mnew);
            lsum *= alpha;
            float ar[4];
#pragma unroll
            for (int r = 0; r < 4; ++r) ar[r] = __shfl(alpha, quad * 4 + r);
#pragma unroll
            for (int dt = 0; dt < 4; ++dt)
#pragma unroll
                for (int r = 0; r < 4; ++r) o[dt][r] *= ar[r];
            mprev = mnew;
        }

        // exp2 against (possibly stale) mprev; lsum stays per-quad partial.
        float psum = 0.f;
#pragma unroll
        for (int st = 0; st < 4; ++st)
#pragma unroll
            for (int r = 0; r < 4; ++r) {
                float pv = EXP2(sc[st][r] - mprev);
                psum += pv;
                sc[st][r] = pv;
            }
        lsum += psum;

        // P in-register: sc[st][r] already in PV A-fragment order.
        bf16x8 pf0, pf1;
#pragma unroll
        for (int r = 0; r < 4; ++r) {
            pf0[r]     = (__bf16)sc[0][r];
            pf0[4 + r] = (__bf16)sc[1][r];
            pf1[r]     = (__bf16)sc[2][r];
            pf1[4 + r] = (__bf16)sc[3][r];
        }
        __builtin_amdgcn_s_setprio(1);
#pragma unroll
        for (int dt = 0; dt < 4; ++dt) {
            o[dt] = __builtin_amdgcn_mfma_f32_16x16x32_bf16(pf0, vb0[dt], o[dt], 0, 0, 0);
            o[dt] = __builtin_amdgcn_mfma_f32_16x16x32_bf16(pf1, vb1[dt], o[dt], 0, 0, 0);
        }
        __builtin_amdgcn_s_setprio(0);
    };

    // -------- merge groups 1..3 into group 0, then store q-tile `qt` --------
    auto merge_store = [&](int qt, f32x4* o, float& mprev, float& lsum) {
        // complete the deferred quad-reduction of lsum (once per phase)
        lsum += __shfl_xor(lsum, 16);
        lsum += __shfl_xor(lsum, 32);
        for (int rr = 1; rr < 4; ++rr) {
            __syncthreads();
            if (grp == rr) {
                if (quad == 0) { mx1[wg * 16 + l15] = mprev; lx1[wg * 16 + l15] = lsum; }
#pragma unroll
                for (int dt = 0; dt < 4; ++dt)
#pragma unroll
                    for (int r = 0; r < 4; ++r)
                        xchg[(wg * 16 + quad * 4 + r) * 65 + dt * 16 + l15] = o[dt][r];
            }
            __syncthreads();
            if (grp == 0) {
#pragma unroll
                for (int r = 0; r < 4; ++r) {
                    const int row = wg * 16 + quad * 4 + r;
                    const float m0r = __shfl(mprev, quad * 4 + r);
                    const float m1r = mx1[row];
                    const float ms  = fmaxf(m0r, m1r);
                    const float w0  = EXP2(m0r - ms);
                    const float w1  = EXP2(m1r - ms);
#pragma unroll
                    for (int dt = 0; dt < 4; ++dt)
                        o[dt][r] = o[dt][r] * w0 + xchg[row * 65 + dt * 16 + l15] * w1;
                }
                const float m1l = mx1[wg * 16 + l15];
                const float msl = fmaxf(mprev, m1l);
                lsum = EXP2(mprev - msl) * lsum + EXP2(m1l - msl) * lx1[wg * 16 + l15];
                mprev = msl;
            }
        }
        if (grp == 0) {
            float rl[4];
#pragma unroll
            for (int r = 0; r < 4; ++r) rl[r] = 1.0f / __shfl(lsum, quad * 4 + r);
            const int orow = qt * 64 + wg * 16 + quad * 4;
#pragma unroll
            for (int dt = 0; dt < 4; ++dt)
#pragma unroll
                for (int r = 0; r < 4; ++r)
                    out[(long)(b * TT + orow + r) * HH + dt * 16 + l15] = o[dt][r] * rl[r];
        }
        __syncthreads();   // xchg/mx1 reusable by next phase
    };

    // ---------------- phase A: q-tile 63-p ----------------
    {
        const int qt = 63 - p;
        const int qrow = qt * 64 + wg * 16 + l15;
        const unsigned short* qbase = q_ws + (b * TT + qrow) * HH;
        const bf16x8 qf0 = *reinterpret_cast<const bf16x8*>(qbase + quad * 8);
        const bf16x8 qf1 = *reinterpret_cast<const bf16x8*>(qbase + 32 + quad * 8);
        f32x4 o[4];
#pragma unroll
        for (int dt = 0; dt < 4; ++dt) o[dt] = zero;
        float mprev = -1e30f, lsum = 0.f;
        for (int t = grp; t <= qt; t += 4)
            do_tile(t, qt, qrow, qf0, qf1, o, mprev, lsum);
        merge_store(qt, o, mprev, lsum);
    }

    // ---------------- phase B: q-tile p ----------------
    {
        const int qt = p;
        const int qrow = qt * 64 + wg * 16 + l15;
        const unsigned short* qbase = q_ws + (b * TT + qrow) * HH;
        const bf16x8 qf0 = *reinterpret_cast<const bf16x8*>(qbase + quad * 8);
        const bf16x8 qf1 = *reinterpret_cast<const bf16x8*>(qbase + 32 + quad * 8);
        f32x4 o[4];
#pragma unroll
        for (int dt = 0; dt < 4; ++dt) o[dt] = zero;
        float mprev = -1e30f, lsum = 0.f;
        for (int t = grp; t <= qt; t += 4)
            do_tile(t, qt, qrow, qf0, qf1, o, mprev, lsum);
        merge_store(qt, o, mprev, lsum);
    }
}

// ---------------------------------------------------------------- launch
extern "C" void kernel_launch(void* const* d_in, const int* in_sizes, int n_in,
                              void* d_out, int out_size, void* d_ws, size_t ws_size,
                              hipStream_t stream) {
    const float* x  = (const float*)d_in[0];
    const float* Wk = (const float*)d_in[1];
    const float* Wq = (const float*)d_in[2];
    const float* Wv = (const float*)d_in[3];
    float* out = (float*)d_out;

    char* ws = (char*)d_ws;
    unsigned short* Wt    = (unsigned short*)(ws);                         // 147456 B
    unsigned short* q_ws  = (unsigned short*)(ws + 147456);                // 4 MiB
    unsigned short* k_ws  = (unsigned short*)(ws + 147456 + 4194304);      // 4 MiB
    unsigned short* vt_ws = (unsigned short*)(ws + 147456 + 2 * 4194304);  // 4 MiB

    wtrans_kernel<<<dim3(6, 3), 256, 0, stream>>>(Wk, Wq, Wv, Wt);
    qkv_kernel<<<NROW / 32, 256, 0, stream>>>(x, Wt, q_ws, k_ws, vt_ws);
    attn_kernel<<<(TT / 128) * BB, 1024, 0, stream>>>(q_ws, k_ws, vt_ws, out);
}